// Round 12
// baseline (118.710 us; speedup 1.0000x reference)
//
#include <hip/hip_runtime.h>

#define AS 20      // alphabet size
#define ASS 400    // AS*AS
#define KK 8
#define BB 256
#define MM 2
#define LL 1024
#define NPOW 12    // powers S^1..S^12 per (m,k)

__device__ __forceinline__ float softplus_f(float x) {
    return x > 20.f ? x : log1pf(expf(x));
}

// wave-synchronous LDS fence (rule #18: lgkmcnt + sched_barrier)
__device__ __forceinline__ void wsync() {
    __builtin_amdgcn_sched_barrier(0);
    asm volatile("s_waitcnt lgkmcnt(0)" ::: "memory");
    __builtin_amdgcn_sched_barrier(0);
}

// wave-level 20x20 matmul C = A*B in LDS, lanes 0..49, 2x4 tiles (proven r4/r10)
__device__ __forceinline__ void mul20w(const float* __restrict__ A,
                                       const float* __restrict__ B,
                                       float* __restrict__ C, int lane) {
    wsync();
    if (lane < 50) {
        const int i2 = (lane / 5) * 2;
        const int c4 = (lane % 5) * 4;
        float a0[AS], a1[AS];
        #pragma unroll
        for (int q = 0; q < 5; q++) {
            float4 v0 = *(const float4*)&A[i2 * AS + 4 * q];
            float4 v1 = *(const float4*)&A[(i2 + 1) * AS + 4 * q];
            a0[4*q] = v0.x; a0[4*q+1] = v0.y; a0[4*q+2] = v0.z; a0[4*q+3] = v0.w;
            a1[4*q] = v1.x; a1[4*q+1] = v1.y; a1[4*q+2] = v1.z; a1[4*q+3] = v1.w;
        }
        float4 s0 = {0.f,0.f,0.f,0.f}, s1 = {0.f,0.f,0.f,0.f};
        #pragma unroll
        for (int z = 0; z < AS; z++) {
            float4 bv = *(const float4*)&B[z * AS + c4];
            s0.x = fmaf(a0[z], bv.x, s0.x); s0.y = fmaf(a0[z], bv.y, s0.y);
            s0.z = fmaf(a0[z], bv.z, s0.z); s0.w = fmaf(a0[z], bv.w, s0.w);
            s1.x = fmaf(a1[z], bv.x, s1.x); s1.y = fmaf(a1[z], bv.y, s1.y);
            s1.z = fmaf(a1[z], bv.z, s1.z); s1.w = fmaf(a1[z], bv.w, s1.w);
        }
        *(float4*)&C[i2 * AS + c4] = s0;
        *(float4*)&C[(i2 + 1) * AS + c4] = s1;
    }
}

// ---- prep: per (m,k) Ssym + powers S^1..S^12 via depth-4 parallel tree ----
__global__ __launch_bounds__(256) void prep_powers_par(
    const float* __restrict__ exch, const float* __restrict__ eqk,
    const float* __restrict__ pmr,
    float* __restrict__ Spow_g,
    float* __restrict__ sp_g, float* __restrict__ isp_g,
    float* __restrict__ rho_g, float* __restrict__ nrm_g)
{
    const int mk = blockIdx.x;
    const int t = threadIdx.x;
    const int w = t >> 6, lane = t & 63;
    __shared__ float p[AS], sp[AS], isp[AS], rowsum[AS], rowabs[AS];
    __shared__ __align__(16) float SL[NPOW * ASS];

    const float* Km = exch + (size_t)mk * ASS;
    const float* ev = eqk + (size_t)mk * AS;

    if (t < AS) {
        float mx = -1e30f;
        for (int i = 0; i < AS; i++) mx = fmaxf(mx, ev[i]);
        float sum = 0.f;
        for (int i = 0; i < AS; i++) sum += expf(ev[i] - mx);
        float pl = expf(ev[t] - mx) / sum;
        p[t] = pl;
        float sq = sqrtf(pl);
        sp[t] = sq; isp[t] = 1.0f / sq;
    }
    if (t == 0) rho_g[mk] = softplus_f(pmr[mk]);
    __syncthreads();

    float* RP   = SL + ASS;
    float* RawS = SL + 2 * ASS;
    for (int f = t; f < ASS; f += 256) {
        int i = f / AS, j = f % AS;
        float Kv = 0.5f * (Km[i*AS+j] + Km[j*AS+i]);
        float Rv = (i == j) ? 0.f : softplus_f(Kv);
        RP[f] = Rv * p[j];
    }
    __syncthreads();
    if (t < AS) {
        float r = 0.f;
        for (int j = 0; j < AS; j++) r += RP[t*AS+j];
        rowsum[t] = r;
    }
    __syncthreads();
    float mue = 0.f;
    for (int i = 0; i < AS; i++) mue += p[i] * rowsum[i];
    const float inv_mue = 1.0f / fmaxf(mue, 1e-16f);
    for (int f = t; f < ASS; f += 256) {
        int i = f / AS, j = f % AS;
        float Qv = (RP[f] - (i == j ? rowsum[i] : 0.f)) * inv_mue;
        RawS[f] = sp[i] * Qv * isp[j];
    }
    __syncthreads();
    for (int f = t; f < ASS; f += 256) {
        int i = f / AS, j = f % AS;
        SL[f] = 0.5f * (RawS[f] + RawS[j*AS+i]);   // S^1
    }
    __syncthreads();
    if (t < AS) {
        float r = 0.f;
        for (int j = 0; j < AS; j++) r += fabsf(SL[t*AS+j]);
        rowabs[t] = r;
    }
    __syncthreads();
    if (t == 0) {
        float n = 0.f;
        for (int i = 0; i < AS; i++) n = fmaxf(n, rowabs[i]);
        nrm_g[mk] = n;
    }
    if (t < AS) { sp_g[mk*AS + t] = sp[t]; isp_g[mk*AS + t] = isp[t]; }

    if (w == 0) mul20w(SL, SL, SL + ASS, lane);                     // S2
    __syncthreads();
    if (w == 0) mul20w(SL + ASS, SL,       SL + 2*ASS, lane);       // S3
    if (w == 1) mul20w(SL + ASS, SL + ASS, SL + 3*ASS, lane);       // S4
    __syncthreads();
    if (w == 0) mul20w(SL + 3*ASS, SL,         SL + 4*ASS, lane);   // S5
    if (w == 1) mul20w(SL + 3*ASS, SL + ASS,   SL + 5*ASS, lane);   // S6
    if (w == 2) mul20w(SL + 3*ASS, SL + 2*ASS, SL + 6*ASS, lane);   // S7
    if (w == 3) mul20w(SL + 3*ASS, SL + 3*ASS, SL + 7*ASS, lane);   // S8
    __syncthreads();
    if (w == 0) mul20w(SL + 7*ASS, SL,         SL + 8*ASS, lane);   // S9
    if (w == 1) mul20w(SL + 7*ASS, SL + ASS,   SL + 9*ASS, lane);   // S10
    if (w == 2) mul20w(SL + 7*ASS, SL + 2*ASS, SL + 10*ASS, lane);  // S11
    if (w == 3) mul20w(SL + 7*ASS, SL + 3*ASS, SL + 11*ASS, lane);  // S12
    __syncthreads();

    float* Sg = Spow_g + (size_t)mk * NPOW * ASS;
    for (int f = t; f < NPOW * ASS; f += 256) Sg[f] = SL[f];
}

// ---- fused: prologue builds 8 P's (Taylor sums + rare squarings), then apply.
// This round: PLAIN cached stores (nt removed — isolating the nt variable).
#define ACC4(A, Sv, Z) \
    A.x = fmaf(Sv, Preg[Z].x, A.x); A.y = fmaf(Sv, Preg[Z].y, A.y); \
    A.z = fmaf(Sv, Preg[Z].z, A.z); A.w = fmaf(Sv, Preg[Z].w, A.w);

__global__ __launch_bounds__(320, 3) void fused_apply(
    const float* __restrict__ seq, const float* __restrict__ Spow_g,
    const float* __restrict__ sp_g, const float* __restrict__ isp_g,
    const float* __restrict__ rho_g, const float* __restrict__ nrm_g,
    const float* __restrict__ tauk, float* __restrict__ out)
{
    const int blk = blockIdx.x;
    const int mb = blk >> 1;
    const int half = blk & 1;
    const int mi = mb / BB;
    const int t = threadIdx.x;
    const int w = t >> 6;
    const int lane = t & 63;

    __shared__ __align__(16) float Plds[KK * ASS];
    __shared__ __align__(16) float4 sbuf[2][320];
    __shared__ __align__(16) float Tmp[5][ASS];
    __shared__ float coefs[KK][NPOW];
    __shared__ float spk[KK * AS], ispk[KK * AS];
    __shared__ float scs[KK];
    __shared__ int ssh[KK];

    const int rowbase = half * (LL / 2);
    const float* seqb = seq + (size_t)mb * LL * AS;
    float* outb = out + (size_t)mb * LL * (KK * AS);

    const float4 first = ((const float4*)(seqb + (size_t)rowbase * AS))[t];

    if (t < KK) {
        const float tau = softplus_f(tauk[mb]) * rho_g[mi * KK + t];
        const float nt = tau * nrm_g[mi * KK + t];
        int s = 0;
        if (nt > 2.0f) {
            s = (int)ceilf(log2f(nt * 0.5f));
            if (s < 0) s = 0;
            if (s > 12) s = 12;
        }
        ssh[t] = s;
        scs[t] = ldexpf(tau, -s);
    }
    if (t < KK * AS) {
        spk[t]  = sp_g [mi * KK * AS + t];
        ispk[t] = isp_g[mi * KK * AS + t];
    }
    __syncthreads();
    if (t < KK * NPOW) {
        const int k = t / NPOW, n = t % NPOW + 1;
        const float sc = scs[k];
        float scp = sc, fact = 1.f;
        for (int q = 2; q <= n; ++q) { scp *= sc; fact *= (float)q; }
        coefs[k][n - 1] = scp / fact;
    }
    __syncthreads();

    {
        const float* Sbase = Spow_g + (size_t)mi * KK * NPOW * ASS;
        #pragma unroll 2
        for (int e = t; e < KK * ASS; e += 320) {
            const int k = e / ASS;
            const int f = e - k * ASS;
            const int i = f / AS, jj = f - i * AS;
            const float* Sg = Sbase + (size_t)k * NPOW * ASS + f;
            float acc = (i == jj) ? 1.f : 0.f;
            #pragma unroll
            for (int n = 1; n <= NPOW; ++n)
                acc = fmaf(coefs[k][n - 1], Sg[(n - 1) * ASS], acc);
            Plds[e] = acc;
        }
    }
    __syncthreads();

    {
        const int nk = (w < 3) ? 2 : 1;
        for (int pi = 0; pi < nk; ++pi) {
            const int k = (pi == 0) ? w : w + 5;
            const int s = ssh[k];
            float* Pk = &Plds[k * ASS];
            float* Tw = &Tmp[w][0];
            for (int q = 0; q < s; ++q) {
                if ((q & 1) == 0) mul20w(Pk, Pk, Tw, lane);
                else              mul20w(Tw, Tw, Pk, lane);
            }
            if (s & 1) {
                wsync();
                if (lane < 50) {
                    #pragma unroll
                    for (int u = 0; u < 8; ++u) Pk[lane * 8 + u] = Tw[lane * 8 + u];
                }
            }
        }
    }
    __syncthreads();

    for (int e = t; e < KK * ASS; e += 320) {
        const int k = e / ASS;
        const int f = e - k * ASS;
        const int i = f / AS, jj = f - i * AS;
        Plds[e] *= ispk[k * AS + i] * spk[k * AS + jj];
    }
    __syncthreads();

    // ---- apply loop (linear store remap, plain stores) ----
    const int j = t % 40;        // col group: cols 4j..4j+3
    const int rg = t / 40;       // row-within-stripe 0..7
    const int ki = j / 5;
    const int s0 = (j % 5) * 4;

    float4 Preg[AS];
    #pragma unroll
    for (int z = 0; z < AS; z++)
        Preg[z] = *(const float4*)&Plds[ki * ASS + z * AS + s0];
    sbuf[0][t] = first;
    __syncthreads();

    float* stbase = outb + (size_t)rowbase * 160 + t * 4;

    for (int c = 0; c < 8; c++) {
        const int cur = c & 1;
        float4 rnext;
        if (c < 7)
            rnext = ((const float4*)(seqb + (size_t)(rowbase + (c + 1) * 64) * AS))[t];
        float* stc = stbase + (size_t)c * 64 * 160;
        #pragma unroll
        for (int pp = 0; pp < 4; pp++) {
            const int lrA = rg + 16 * pp;
            const int lrB = lrA + 8;
            const float4* rowA = &sbuf[cur][lrA * 5];
            const float4* rowB = &sbuf[cur][lrB * 5];
            float4 a0 = {0.f,0.f,0.f,0.f}, a1 = {0.f,0.f,0.f,0.f};
            #pragma unroll
            for (int q = 0; q < 5; q++) {
                float4 svA = rowA[q];
                float4 svB = rowB[q];
                ACC4(a0, svA.x, 4*q+0)  ACC4(a1, svB.x, 4*q+0)
                ACC4(a0, svA.y, 4*q+1)  ACC4(a1, svB.y, 4*q+1)
                ACC4(a0, svA.z, 4*q+2)  ACC4(a1, svB.z, 4*q+2)
                ACC4(a0, svA.w, 4*q+3)  ACC4(a1, svB.w, 4*q+3)
            }
            *(float4*)(stc + pp * 2560)        = a0;   // rows rg+16pp
            *(float4*)(stc + pp * 2560 + 1280) = a1;   // rows rg+16pp+8
        }
        if (c < 7) sbuf[cur ^ 1][t] = rnext;
        __syncthreads();
    }
}

extern "C" void kernel_launch(void* const* d_in, const int* in_sizes, int n_in,
                              void* d_out, int out_size, void* d_ws, size_t ws_size,
                              hipStream_t stream) {
    const float* seq  = (const float*)d_in[0];
    const float* exch = (const float*)d_in[1];
    const float* eqk  = (const float*)d_in[2];
    const float* tauk = (const float*)d_in[3];
    const float* pmr  = (const float*)d_in[4];
    float* out = (float*)d_out;

    float* ws   = (float*)d_ws;
    float* Spow = ws;
    float* spg  = Spow + (size_t)MM * KK * NPOW * ASS;
    float* ispg = spg + MM * KK * AS;
    float* rhog = ispg + MM * KK * AS;
    float* nrmg = rhog + MM * KK;

    prep_powers_par<<<dim3(MM * KK), dim3(256), 0, stream>>>(
        exch, eqk, pmr, Spow, spg, ispg, rhog, nrmg);
    fused_apply<<<dim3(MM * BB * 2), dim3(320), 0, stream>>>(
        seq, Spow, spg, ispg, rhog, nrmg, tauk, out);
}

// Round 13
// 105.993 us; speedup vs baseline: 1.1200x; 1.1200x over previous
//
#include <hip/hip_runtime.h>

#define AS 20      // alphabet size
#define ASS 400    // AS*AS
#define KK 8
#define BB 256
#define MM 2
#define LL 1024
#define NPOW 12    // powers S^1..S^12 per (m,k)

typedef float nfloat4 __attribute__((ext_vector_type(4)));

__device__ __forceinline__ float softplus_f(float x) {
    return x > 20.f ? x : log1pf(expf(x));
}

// wave-synchronous LDS fence (rule #18: lgkmcnt + sched_barrier)
__device__ __forceinline__ void wsync() {
    __builtin_amdgcn_sched_barrier(0);
    asm volatile("s_waitcnt lgkmcnt(0)" ::: "memory");
    __builtin_amdgcn_sched_barrier(0);
}

// wave-level 20x20 matmul C = A*B in LDS, lanes 0..49, 2x4 tiles (proven r4/r10)
__device__ __forceinline__ void mul20w(const float* __restrict__ A,
                                       const float* __restrict__ B,
                                       float* __restrict__ C, int lane) {
    wsync();
    if (lane < 50) {
        const int i2 = (lane / 5) * 2;
        const int c4 = (lane % 5) * 4;
        float a0[AS], a1[AS];
        #pragma unroll
        for (int q = 0; q < 5; q++) {
            float4 v0 = *(const float4*)&A[i2 * AS + 4 * q];
            float4 v1 = *(const float4*)&A[(i2 + 1) * AS + 4 * q];
            a0[4*q] = v0.x; a0[4*q+1] = v0.y; a0[4*q+2] = v0.z; a0[4*q+3] = v0.w;
            a1[4*q] = v1.x; a1[4*q+1] = v1.y; a1[4*q+2] = v1.z; a1[4*q+3] = v1.w;
        }
        float4 s0 = {0.f,0.f,0.f,0.f}, s1 = {0.f,0.f,0.f,0.f};
        #pragma unroll
        for (int z = 0; z < AS; z++) {
            float4 bv = *(const float4*)&B[z * AS + c4];
            s0.x = fmaf(a0[z], bv.x, s0.x); s0.y = fmaf(a0[z], bv.y, s0.y);
            s0.z = fmaf(a0[z], bv.z, s0.z); s0.w = fmaf(a0[z], bv.w, s0.w);
            s1.x = fmaf(a1[z], bv.x, s1.x); s1.y = fmaf(a1[z], bv.y, s1.y);
            s1.z = fmaf(a1[z], bv.z, s1.z); s1.w = fmaf(a1[z], bv.w, s1.w);
        }
        *(float4*)&C[i2 * AS + c4] = s0;
        *(float4*)&C[(i2 + 1) * AS + c4] = s1;
    }
}

// ---- prep: per (m,k) Ssym + powers S^1..S^12 via depth-4 parallel tree ----
__global__ __launch_bounds__(256) void prep_powers_par(
    const float* __restrict__ exch, const float* __restrict__ eqk,
    const float* __restrict__ pmr,
    float* __restrict__ Spow_g,
    float* __restrict__ sp_g, float* __restrict__ isp_g,
    float* __restrict__ rho_g, float* __restrict__ nrm_g)
{
    const int mk = blockIdx.x;
    const int t = threadIdx.x;
    const int w = t >> 6, lane = t & 63;
    __shared__ float p[AS], sp[AS], isp[AS], rowsum[AS], rowabs[AS];
    __shared__ __align__(16) float SL[NPOW * ASS];

    const float* Km = exch + (size_t)mk * ASS;
    const float* ev = eqk + (size_t)mk * AS;

    if (t < AS) {
        float mx = -1e30f;
        for (int i = 0; i < AS; i++) mx = fmaxf(mx, ev[i]);
        float sum = 0.f;
        for (int i = 0; i < AS; i++) sum += expf(ev[i] - mx);
        float pl = expf(ev[t] - mx) / sum;
        p[t] = pl;
        float sq = sqrtf(pl);
        sp[t] = sq; isp[t] = 1.0f / sq;
    }
    if (t == 0) rho_g[mk] = softplus_f(pmr[mk]);
    __syncthreads();

    float* RP   = SL + ASS;
    float* RawS = SL + 2 * ASS;
    for (int f = t; f < ASS; f += 256) {
        int i = f / AS, j = f % AS;
        float Kv = 0.5f * (Km[i*AS+j] + Km[j*AS+i]);
        float Rv = (i == j) ? 0.f : softplus_f(Kv);
        RP[f] = Rv * p[j];
    }
    __syncthreads();
    if (t < AS) {
        float r = 0.f;
        for (int j = 0; j < AS; j++) r += RP[t*AS+j];
        rowsum[t] = r;
    }
    __syncthreads();
    float mue = 0.f;
    for (int i = 0; i < AS; i++) mue += p[i] * rowsum[i];
    const float inv_mue = 1.0f / fmaxf(mue, 1e-16f);
    for (int f = t; f < ASS; f += 256) {
        int i = f / AS, j = f % AS;
        float Qv = (RP[f] - (i == j ? rowsum[i] : 0.f)) * inv_mue;
        RawS[f] = sp[i] * Qv * isp[j];
    }
    __syncthreads();
    for (int f = t; f < ASS; f += 256) {
        int i = f / AS, j = f % AS;
        SL[f] = 0.5f * (RawS[f] + RawS[j*AS+i]);   // S^1
    }
    __syncthreads();
    if (t < AS) {
        float r = 0.f;
        for (int j = 0; j < AS; j++) r += fabsf(SL[t*AS+j]);
        rowabs[t] = r;
    }
    __syncthreads();
    if (t == 0) {
        float n = 0.f;
        for (int i = 0; i < AS; i++) n = fmaxf(n, rowabs[i]);
        nrm_g[mk] = n;
    }
    if (t < AS) { sp_g[mk*AS + t] = sp[t]; isp_g[mk*AS + t] = isp[t]; }

    if (w == 0) mul20w(SL, SL, SL + ASS, lane);                     // S2
    __syncthreads();
    if (w == 0) mul20w(SL + ASS, SL,       SL + 2*ASS, lane);       // S3
    if (w == 1) mul20w(SL + ASS, SL + ASS, SL + 3*ASS, lane);       // S4
    __syncthreads();
    if (w == 0) mul20w(SL + 3*ASS, SL,         SL + 4*ASS, lane);   // S5
    if (w == 1) mul20w(SL + 3*ASS, SL + ASS,   SL + 5*ASS, lane);   // S6
    if (w == 2) mul20w(SL + 3*ASS, SL + 2*ASS, SL + 6*ASS, lane);   // S7
    if (w == 3) mul20w(SL + 3*ASS, SL + 3*ASS, SL + 7*ASS, lane);   // S8
    __syncthreads();
    if (w == 0) mul20w(SL + 7*ASS, SL,         SL + 8*ASS, lane);   // S9
    if (w == 1) mul20w(SL + 7*ASS, SL + ASS,   SL + 9*ASS, lane);   // S10
    if (w == 2) mul20w(SL + 7*ASS, SL + 2*ASS, SL + 10*ASS, lane);  // S11
    if (w == 3) mul20w(SL + 7*ASS, SL + 3*ASS, SL + 11*ASS, lane);  // S12
    __syncthreads();

    float* Sg = Spow_g + (size_t)mk * NPOW * ASS;
    for (int f = t; f < NPOW * ASS; f += 256) Sg[f] = SL[f];
}

// ---- fused: prologue (Taylor sums + rare squarings), then apply with NT
// stores. LDS shrunk: squaring scratch aliases sbuf (disjoint lifetimes)
// -> ~24KB/block -> 4 blocks/CU -> ALL 1024 blocks co-resident (no tail).
#define ACC4(A, Sv, Z) \
    A.x = fmaf(Sv, Preg[Z].x, A.x); A.y = fmaf(Sv, Preg[Z].y, A.y); \
    A.z = fmaf(Sv, Preg[Z].z, A.z); A.w = fmaf(Sv, Preg[Z].w, A.w);

__device__ __forceinline__ void nt_store4(float4 v, float* p) {
    nfloat4 nv; nv.x = v.x; nv.y = v.y; nv.z = v.z; nv.w = v.w;
    __builtin_nontemporal_store(nv, (nfloat4*)p);
}

__global__ __launch_bounds__(320, 4) void fused_apply(
    const float* __restrict__ seq, const float* __restrict__ Spow_g,
    const float* __restrict__ sp_g, const float* __restrict__ isp_g,
    const float* __restrict__ rho_g, const float* __restrict__ nrm_g,
    const float* __restrict__ tauk, float* __restrict__ out)
{
    const int blk = blockIdx.x;
    const int mb = blk >> 1;
    const int half = blk & 1;
    const int mi = mb / BB;
    const int t = threadIdx.x;
    const int w = t >> 6;
    const int lane = t & 63;

    __shared__ __align__(16) float Plds[KK * ASS];   // 12.8 KB
    __shared__ __align__(16) float4 sbuf[2][320];    // 10.24 KB (also Tmp)
    __shared__ float coefs[KK][NPOW];
    __shared__ float spk[KK * AS], ispk[KK * AS];
    __shared__ float scs[KK];
    __shared__ int ssh[KK];

    float* Tmp = (float*)sbuf;   // squaring scratch: 5*400*4=8000B <= 10240B

    const int rowbase = half * (LL / 2);
    const float* seqb = seq + (size_t)mb * LL * AS;
    float* outb = out + (size_t)mb * LL * (KK * AS);

    const float4 first = ((const float4*)(seqb + (size_t)rowbase * AS))[t];

    if (t < KK) {
        const float tau = softplus_f(tauk[mb]) * rho_g[mi * KK + t];
        const float nt = tau * nrm_g[mi * KK + t];
        int s = 0;
        if (nt > 2.0f) {
            s = (int)ceilf(log2f(nt * 0.5f));
            if (s < 0) s = 0;
            if (s > 12) s = 12;
        }
        ssh[t] = s;
        scs[t] = ldexpf(tau, -s);
    }
    if (t < KK * AS) {
        spk[t]  = sp_g [mi * KK * AS + t];
        ispk[t] = isp_g[mi * KK * AS + t];
    }
    __syncthreads();
    if (t < KK * NPOW) {
        const int k = t / NPOW, n = t % NPOW + 1;
        const float sc = scs[k];
        float scp = sc, fact = 1.f;
        for (int q = 2; q <= n; ++q) { scp *= sc; fact *= (float)q; }
        coefs[k][n - 1] = scp / fact;
    }
    __syncthreads();

    {
        const float* Sbase = Spow_g + (size_t)mi * KK * NPOW * ASS;
        #pragma unroll 2
        for (int e = t; e < KK * ASS; e += 320) {
            const int k = e / ASS;
            const int f = e - k * ASS;
            const int i = f / AS, jj = f - i * AS;
            const float* Sg = Sbase + (size_t)k * NPOW * ASS + f;
            float acc = (i == jj) ? 1.f : 0.f;
            #pragma unroll
            for (int n = 1; n <= NPOW; ++n)
                acc = fmaf(coefs[k][n - 1], Sg[(n - 1) * ASS], acc);
            Plds[e] = acc;
        }
    }
    __syncthreads();

    {
        const int nk = (w < 3) ? 2 : 1;
        for (int pi = 0; pi < nk; ++pi) {
            const int k = (pi == 0) ? w : w + 5;
            const int s = ssh[k];
            float* Pk = &Plds[k * ASS];
            float* Tw = &Tmp[w * ASS];
            for (int q = 0; q < s; ++q) {
                if ((q & 1) == 0) mul20w(Pk, Pk, Tw, lane);
                else              mul20w(Tw, Tw, Pk, lane);
            }
            if (s & 1) {
                wsync();
                if (lane < 50) {
                    #pragma unroll
                    for (int u = 0; u < 8; ++u) Pk[lane * 8 + u] = Tw[lane * 8 + u];
                }
            }
        }
    }
    __syncthreads();

    for (int e = t; e < KK * ASS; e += 320) {
        const int k = e / ASS;
        const int f = e - k * ASS;
        const int i = f / AS, jj = f - i * AS;
        Plds[e] *= ispk[k * AS + i] * spk[k * AS + jj];
    }
    __syncthreads();

    // ---- apply loop (linear store map, NT stores) ----
    const int j = t % 40;        // col group: cols 4j..4j+3
    const int rg = t / 40;       // row-within-stripe 0..7
    const int ki = j / 5;
    const int s0 = (j % 5) * 4;

    float4 Preg[AS];
    #pragma unroll
    for (int z = 0; z < AS; z++)
        Preg[z] = *(const float4*)&Plds[ki * ASS + z * AS + s0];
    __syncthreads();             // Tmp/sbuf alias boundary
    sbuf[0][t] = first;
    __syncthreads();

    float* stbase = outb + (size_t)rowbase * 160 + t * 4;

    for (int c = 0; c < 8; c++) {
        const int cur = c & 1;
        float4 rnext;
        if (c < 7)
            rnext = ((const float4*)(seqb + (size_t)(rowbase + (c + 1) * 64) * AS))[t];
        float* stc = stbase + (size_t)c * 64 * 160;
        #pragma unroll
        for (int pp = 0; pp < 4; pp++) {
            const int lrA = rg + 16 * pp;
            const int lrB = lrA + 8;
            const float4* rowA = &sbuf[cur][lrA * 5];
            const float4* rowB = &sbuf[cur][lrB * 5];
            float4 a0 = {0.f,0.f,0.f,0.f}, a1 = {0.f,0.f,0.f,0.f};
            #pragma unroll
            for (int q = 0; q < 5; q++) {
                float4 svA = rowA[q];
                float4 svB = rowB[q];
                ACC4(a0, svA.x, 4*q+0)  ACC4(a1, svB.x, 4*q+0)
                ACC4(a0, svA.y, 4*q+1)  ACC4(a1, svB.y, 4*q+1)
                ACC4(a0, svA.z, 4*q+2)  ACC4(a1, svB.z, 4*q+2)
                ACC4(a0, svA.w, 4*q+3)  ACC4(a1, svB.w, 4*q+3)
            }
            nt_store4(a0, stc + pp * 2560);          // rows rg+16pp
            nt_store4(a1, stc + pp * 2560 + 1280);   // rows rg+16pp+8
        }
        if (c < 7) sbuf[cur ^ 1][t] = rnext;
        __syncthreads();
    }
}

extern "C" void kernel_launch(void* const* d_in, const int* in_sizes, int n_in,
                              void* d_out, int out_size, void* d_ws, size_t ws_size,
                              hipStream_t stream) {
    const float* seq  = (const float*)d_in[0];
    const float* exch = (const float*)d_in[1];
    const float* eqk  = (const float*)d_in[2];
    const float* tauk = (const float*)d_in[3];
    const float* pmr  = (const float*)d_in[4];
    float* out = (float*)d_out;

    float* ws   = (float*)d_ws;
    float* Spow = ws;
    float* spg  = Spow + (size_t)MM * KK * NPOW * ASS;
    float* ispg = spg + MM * KK * AS;
    float* rhog = ispg + MM * KK * AS;
    float* nrmg = rhog + MM * KK;

    prep_powers_par<<<dim3(MM * KK), dim3(256), 0, stream>>>(
        exch, eqk, pmr, Spow, spg, ispg, rhog, nrmg);
    fused_apply<<<dim3(MM * BB * 2), dim3(320), 0, stream>>>(
        seq, Spow, spg, ispg, rhog, nrmg, tauk, out);
}

// Round 14
// 85.613 us; speedup vs baseline: 1.3866x; 1.2380x over previous
//
#include <hip/hip_runtime.h>

#define AS 20      // alphabet size
#define ASS 400    // AS*AS
#define KK 8
#define BB 256
#define MM 2
#define LL 1024
#define NPOW 12    // powers S^1..S^12 per (m,k)

typedef __attribute__((ext_vector_type(8))) short bf16x8;
typedef __attribute__((ext_vector_type(16))) float f32x16;

__device__ __forceinline__ unsigned short f2bf(float x) {   // f32 -> bf16 RNE
    unsigned int u = __builtin_bit_cast(unsigned int, x);
    u += 0x7FFFu + ((u >> 16) & 1u);
    return (unsigned short)(u >> 16);
}

__device__ __forceinline__ float softplus_f(float x) {
    return x > 20.f ? x : log1pf(expf(x));
}

// wave-synchronous LDS fence (rule #18)
__device__ __forceinline__ void wsync() {
    __builtin_amdgcn_sched_barrier(0);
    asm volatile("s_waitcnt lgkmcnt(0)" ::: "memory");
    __builtin_amdgcn_sched_barrier(0);
}

// wave-level 20x20 matmul C = A*B in LDS, lanes 0..49, 2x4 tiles (proven)
__device__ __forceinline__ void mul20w(const float* __restrict__ A,
                                       const float* __restrict__ B,
                                       float* __restrict__ C, int lane) {
    wsync();
    if (lane < 50) {
        const int i2 = (lane / 5) * 2;
        const int c4 = (lane % 5) * 4;
        float a0[AS], a1[AS];
        #pragma unroll
        for (int q = 0; q < 5; q++) {
            float4 v0 = *(const float4*)&A[i2 * AS + 4 * q];
            float4 v1 = *(const float4*)&A[(i2 + 1) * AS + 4 * q];
            a0[4*q] = v0.x; a0[4*q+1] = v0.y; a0[4*q+2] = v0.z; a0[4*q+3] = v0.w;
            a1[4*q] = v1.x; a1[4*q+1] = v1.y; a1[4*q+2] = v1.z; a1[4*q+3] = v1.w;
        }
        float4 s0 = {0.f,0.f,0.f,0.f}, s1 = {0.f,0.f,0.f,0.f};
        #pragma unroll
        for (int z = 0; z < AS; z++) {
            float4 bv = *(const float4*)&B[z * AS + c4];
            s0.x = fmaf(a0[z], bv.x, s0.x); s0.y = fmaf(a0[z], bv.y, s0.y);
            s0.z = fmaf(a0[z], bv.z, s0.z); s0.w = fmaf(a0[z], bv.w, s0.w);
            s1.x = fmaf(a1[z], bv.x, s1.x); s1.y = fmaf(a1[z], bv.y, s1.y);
            s1.z = fmaf(a1[z], bv.z, s1.z); s1.w = fmaf(a1[z], bv.w, s1.w);
        }
        *(float4*)&C[i2 * AS + c4] = s0;
        *(float4*)&C[(i2 + 1) * AS + c4] = s1;
    }
}

// ---- prep: per (m,k) Ssym + powers S^1..S^12 via depth-4 parallel tree ----
__global__ __launch_bounds__(256) void prep_powers_par(
    const float* __restrict__ exch, const float* __restrict__ eqk,
    const float* __restrict__ pmr,
    float* __restrict__ Spow_g,
    float* __restrict__ sp_g, float* __restrict__ isp_g,
    float* __restrict__ rho_g, float* __restrict__ nrm_g)
{
    const int mk = blockIdx.x;
    const int t = threadIdx.x;
    const int w = t >> 6, lane = t & 63;
    __shared__ float p[AS], sp[AS], isp[AS], rowsum[AS], rowabs[AS];
    __shared__ __align__(16) float SL[NPOW * ASS];

    const float* Km = exch + (size_t)mk * ASS;
    const float* ev = eqk + (size_t)mk * AS;

    if (t < AS) {
        float mx = -1e30f;
        for (int i = 0; i < AS; i++) mx = fmaxf(mx, ev[i]);
        float sum = 0.f;
        for (int i = 0; i < AS; i++) sum += expf(ev[i] - mx);
        float pl = expf(ev[t] - mx) / sum;
        p[t] = pl;
        float sq = sqrtf(pl);
        sp[t] = sq; isp[t] = 1.0f / sq;
    }
    if (t == 0) rho_g[mk] = softplus_f(pmr[mk]);
    __syncthreads();

    float* RP   = SL + ASS;
    float* RawS = SL + 2 * ASS;
    for (int f = t; f < ASS; f += 256) {
        int i = f / AS, j = f % AS;
        float Kv = 0.5f * (Km[i*AS+j] + Km[j*AS+i]);
        float Rv = (i == j) ? 0.f : softplus_f(Kv);
        RP[f] = Rv * p[j];
    }
    __syncthreads();
    if (t < AS) {
        float r = 0.f;
        for (int j = 0; j < AS; j++) r += RP[t*AS+j];
        rowsum[t] = r;
    }
    __syncthreads();
    float mue = 0.f;
    for (int i = 0; i < AS; i++) mue += p[i] * rowsum[i];
    const float inv_mue = 1.0f / fmaxf(mue, 1e-16f);
    for (int f = t; f < ASS; f += 256) {
        int i = f / AS, j = f % AS;
        float Qv = (RP[f] - (i == j ? rowsum[i] : 0.f)) * inv_mue;
        RawS[f] = sp[i] * Qv * isp[j];
    }
    __syncthreads();
    for (int f = t; f < ASS; f += 256) {
        int i = f / AS, j = f % AS;
        SL[f] = 0.5f * (RawS[f] + RawS[j*AS+i]);   // S^1
    }
    __syncthreads();
    if (t < AS) {
        float r = 0.f;
        for (int j = 0; j < AS; j++) r += fabsf(SL[t*AS+j]);
        rowabs[t] = r;
    }
    __syncthreads();
    if (t == 0) {
        float n = 0.f;
        for (int i = 0; i < AS; i++) n = fmaxf(n, rowabs[i]);
        nrm_g[mk] = n;
    }
    if (t < AS) { sp_g[mk*AS + t] = sp[t]; isp_g[mk*AS + t] = isp[t]; }

    if (w == 0) mul20w(SL, SL, SL + ASS, lane);                     // S2
    __syncthreads();
    if (w == 0) mul20w(SL + ASS, SL,       SL + 2*ASS, lane);       // S3
    if (w == 1) mul20w(SL + ASS, SL + ASS, SL + 3*ASS, lane);       // S4
    __syncthreads();
    if (w == 0) mul20w(SL + 3*ASS, SL,         SL + 4*ASS, lane);   // S5
    if (w == 1) mul20w(SL + 3*ASS, SL + ASS,   SL + 5*ASS, lane);   // S6
    if (w == 2) mul20w(SL + 3*ASS, SL + 2*ASS, SL + 6*ASS, lane);   // S7
    if (w == 3) mul20w(SL + 3*ASS, SL + 3*ASS, SL + 7*ASS, lane);   // S8
    __syncthreads();
    if (w == 0) mul20w(SL + 7*ASS, SL,         SL + 8*ASS, lane);   // S9
    if (w == 1) mul20w(SL + 7*ASS, SL + ASS,   SL + 9*ASS, lane);   // S10
    if (w == 2) mul20w(SL + 7*ASS, SL + 2*ASS, SL + 10*ASS, lane);  // S11
    if (w == 3) mul20w(SL + 7*ASS, SL + 3*ASS, SL + 11*ASS, lane);  // S12
    __syncthreads();

    float* Sg = Spow_g + (size_t)mk * NPOW * ASS;
    for (int f = t; f < NPOW * ASS; f += 256) Sg[f] = SL[f];
}

// ---- fused: prologue builds 8 P's (f32), extracts bf16 B-frags to regs;
// apply = bf16 MFMA per 32x32 tile, NT dword stores (2 full 128B lines/instr).
__global__ __launch_bounds__(320, 4) void fused_apply(
    const float* __restrict__ seq, const float* __restrict__ Spow_g,
    const float* __restrict__ sp_g, const float* __restrict__ isp_g,
    const float* __restrict__ rho_g, const float* __restrict__ nrm_g,
    const float* __restrict__ tauk, float* __restrict__ out)
{
    const int blk = blockIdx.x;
    const int mb = blk >> 1;
    const int half = blk & 1;
    const int mi = mb / BB;
    const int t = threadIdx.x;
    const int w = t >> 6;
    const int lane = t & 63;

    // regionA: Plds f32 (12.8KB) during prologue; bf16 tiles [2][64][40] after
    __shared__ __align__(16) float regionA[KK * ASS];
    __shared__ __align__(16) float Tmp[5 * ASS];
    __shared__ float coefs[KK][NPOW];
    __shared__ float spk[KK * AS], ispk[KK * AS];
    __shared__ float scs[KK];
    __shared__ int ssh[KK];

    float* Plds = regionA;

    const int rowbase = half * (LL / 2);
    const float* seqb = seq + (size_t)mb * LL * AS;
    float* outb = out + (size_t)mb * LL * (KK * AS);

    const float4 first = ((const float4*)(seqb + (size_t)rowbase * AS))[t];

    if (t < KK) {
        const float tau = softplus_f(tauk[mb]) * rho_g[mi * KK + t];
        const float nt = tau * nrm_g[mi * KK + t];
        int s = 0;
        if (nt > 2.0f) {
            s = (int)ceilf(log2f(nt * 0.5f));
            if (s < 0) s = 0;
            if (s > 12) s = 12;
        }
        ssh[t] = s;
        scs[t] = ldexpf(tau, -s);
    }
    if (t < KK * AS) {
        spk[t]  = sp_g [mi * KK * AS + t];
        ispk[t] = isp_g[mi * KK * AS + t];
    }
    __syncthreads();
    if (t < KK * NPOW) {
        const int k = t / NPOW, n = t % NPOW + 1;
        const float sc = scs[k];
        float scp = sc, fact = 1.f;
        for (int q = 2; q <= n; ++q) { scp *= sc; fact *= (float)q; }
        coefs[k][n - 1] = scp / fact;
    }
    __syncthreads();

    {   // Taylor sums: Plds[k][f] = I + sum_n coef[k][n] * S^n[f]
        const float* Sbase = Spow_g + (size_t)mi * KK * NPOW * ASS;
        #pragma unroll 2
        for (int e = t; e < KK * ASS; e += 320) {
            const int k = e / ASS;
            const int f = e - k * ASS;
            const int i = f / AS, jj = f - i * AS;
            const float* Sg = Sbase + (size_t)k * NPOW * ASS + f;
            float acc = (i == jj) ? 1.f : 0.f;
            #pragma unroll
            for (int n = 1; n <= NPOW; ++n)
                acc = fmaf(coefs[k][n - 1], Sg[(n - 1) * ASS], acc);
            Plds[e] = acc;
        }
    }
    __syncthreads();

    {   // rare squarings: wave w owns k=w (and k=w+5 for w<3); s wave-uniform
        const int nk = (w < 3) ? 2 : 1;
        for (int pi = 0; pi < nk; ++pi) {
            const int k = (pi == 0) ? w : w + 5;
            const int s = ssh[k];
            float* Pk = &Plds[k * ASS];
            float* Tw = &Tmp[w * ASS];
            for (int q = 0; q < s; ++q) {
                if ((q & 1) == 0) mul20w(Pk, Pk, Tw, lane);
                else              mul20w(Tw, Tw, Pk, lane);
            }
            if (s & 1) {
                wsync();
                if (lane < 50) {
                    #pragma unroll
                    for (int u = 0; u < 8; ++u) Pk[lane * 8 + u] = Tw[lane * 8 + u];
                }
            }
        }
    }
    __syncthreads();

    // diag scale: P = diag(isp) * E * diag(sp)
    for (int e = t; e < KK * ASS; e += 320) {
        const int k = e / ASS;
        const int f = e - k * ASS;
        const int i = f / AS, jj = f - i * AS;
        Plds[e] *= ispk[k * AS + i] * spk[k * AS + jj];
    }
    __syncthreads();

    // ---- B-fragment extraction (bf16, registers). Wave w owns cols
    // [w*32, w*32+32). k-slot mapping k(l,j) = khalf*16 + (l>>5)*8 + j —
    // used identically for A and B, so any true HW K-wiring gives Σ_k A·B.
    const int mycol = w * 32 + (lane & 31);
    const int bki = mycol / 20, bs = mycol % 20;
    const float* Pcol = Plds + bki * ASS + bs;   // + k*20
    bf16x8 bf0, bf1;
    #pragma unroll
    for (int jj = 0; jj < 8; ++jj) {
        const int k0 = (lane >> 5) * 8 + jj;     // khalf 0: k in [0,16)
        const int k1 = 16 + k0;                  // khalf 1: k in [16,32)
        bf0[jj] = (short)f2bf(Pcol[k0 * AS]);    // k0 < 20 always
        bf1[jj] = (k1 < AS) ? (short)f2bf(Pcol[k1 * AS]) : (short)0;
    }
    __syncthreads();   // everyone done reading Plds -> alias as bf16 tiles

    // bf16 seq tiles: [2 bufs][64 rows][40 ushort] (k 0..31 used, 20..31 = 0)
    unsigned short* tile = (unsigned short*)regionA;
    for (int i = t; i < 384; i += 320) {         // zero k-pad both buffers
        const int b = i / 192, r = (i % 192) / 3, q = i % 3;
        *(uint2*)((char*)tile + b * 5120 + r * 80 + 40 + q * 8) = make_uint2(0u, 0u);
    }
    {   // stage chunk 0 (prefetched)
        const int r = t / 5, pc = t % 5;
        const unsigned int lo = (unsigned)f2bf(first.x) | ((unsigned)f2bf(first.y) << 16);
        const unsigned int hi = (unsigned)f2bf(first.z) | ((unsigned)f2bf(first.w) << 16);
        *(uint2*)((char*)tile + r * 80 + pc * 8) = make_uint2(lo, hi);
    }
    __syncthreads();

    for (int c = 0; c < 8; ++c) {
        const int cur = c & 1;
        float4 rnext;
        if (c < 7)
            rnext = ((const float4*)(seqb + (size_t)(rowbase + (c + 1) * 64) * AS))[t];

        const char* tb = (const char*)tile + cur * 5120;
        float* chout = outb + (size_t)(rowbase + c * 64) * 160;

        #pragma unroll
        for (int tr = 0; tr < 2; ++tr) {
            const char* arow = tb + (tr * 32 + (lane & 31)) * 80 + (lane >> 5) * 16;
            const bf16x8 a0 = *(const bf16x8*)(arow);        // k 0..15 slots
            const bf16x8 a1 = *(const bf16x8*)(arow + 32);   // k 16..31 slots
            f32x16 d = {0.f,0.f,0.f,0.f,0.f,0.f,0.f,0.f,
                        0.f,0.f,0.f,0.f,0.f,0.f,0.f,0.f};
            d = __builtin_amdgcn_mfma_f32_32x32x16_bf16(a0, bf0, d, 0, 0, 0);
            d = __builtin_amdgcn_mfma_f32_32x32x16_bf16(a1, bf1, d, 0, 0, 0);
            // D: col = lane&31, row = (reg&3) + 8*(reg>>2) + 4*(lane>>5)
            float* sb = chout + (size_t)(tr * 32 + (lane >> 5) * 4) * 160
                        + w * 32 + (lane & 31);
            #pragma unroll
            for (int r = 0; r < 16; ++r) {
                const int rl = (r & 3) + 8 * (r >> 2);
                __builtin_nontemporal_store(d[r], sb + rl * 160);
            }
        }

        if (c < 7) {   // stage chunk c+1 into the other buffer
            const int r = t / 5, pc = t % 5;
            const unsigned int lo = (unsigned)f2bf(rnext.x) | ((unsigned)f2bf(rnext.y) << 16);
            const unsigned int hi = (unsigned)f2bf(rnext.z) | ((unsigned)f2bf(rnext.w) << 16);
            *(uint2*)((char*)tile + (cur ^ 1) * 5120 + r * 80 + pc * 8) = make_uint2(lo, hi);
        }
        __syncthreads();
    }
}

extern "C" void kernel_launch(void* const* d_in, const int* in_sizes, int n_in,
                              void* d_out, int out_size, void* d_ws, size_t ws_size,
                              hipStream_t stream) {
    const float* seq  = (const float*)d_in[0];
    const float* exch = (const float*)d_in[1];
    const float* eqk  = (const float*)d_in[2];
    const float* tauk = (const float*)d_in[3];
    const float* pmr  = (const float*)d_in[4];
    float* out = (float*)d_out;

    float* ws   = (float*)d_ws;
    float* Spow = ws;
    float* spg  = Spow + (size_t)MM * KK * NPOW * ASS;
    float* ispg = spg + MM * KK * AS;
    float* rhog = ispg + MM * KK * AS;
    float* nrmg = rhog + MM * KK;

    prep_powers_par<<<dim3(MM * KK), dim3(256), 0, stream>>>(
        exch, eqk, pmr, Spow, spg, ispg, rhog, nrmg);
    fused_apply<<<dim3(MM * BB * 2), dim3(320), 0, stream>>>(
        seq, Spow, spg, ispg, rhog, nrmg, tauk, out);
}